// Round 9
// baseline (163.459 us; speedup 1.0000x reference)
//
#include <hip/hip_runtime.h>
#include <cstdint>
#include <cstddef>

typedef unsigned short u16;
typedef __attribute__((ext_vector_type(8))) short s16x8;
typedef __attribute__((ext_vector_type(8))) u16 u16x8;
typedef __attribute__((ext_vector_type(4))) float f32x4;

#define DEV static __device__ __forceinline__
#define GPTR(p) (const __attribute__((address_space(1))) void*)(p)
#define LPTR(p) (__attribute__((address_space(3))) void*)(p)
#define BAR __builtin_amdgcn_s_barrier()
#define SETP1 __builtin_amdgcn_s_setprio(1)
#define SETP0 __builtin_amdgcn_s_setprio(0)

DEV float b2f(u16 u) { union { unsigned i; float f; } c; c.i = ((unsigned)u) << 16; return c.f; }
DEV u16 f2b(float f) {
  union { float f; unsigned i; } c; c.f = f;
  unsigned r = (c.i + 0x7fffu + ((c.i >> 16) & 1u)) >> 16;
  return (u16)r;
}
DEV float sigm(float x) { return 1.0f / (1.0f + __expf(-x)); }

// ---------------------------------------------------------------------------
// Pack gate weights (f32 in) into concatenated bf16 [N,1536]:
//   WZR rows 0..1023    = [W_xz | W_hz | W_mz]
//   WZR rows 1024..2047 = [W_xr | W_hr | W_mr]
//   WH  rows 0..1023    = [W_xh | W_hh | W_mh]
// plus bf16 copy of W_gamma_h -> WGH [1024,256].
// ---------------------------------------------------------------------------
__global__ __launch_bounds__(256) void pack_w(
    const float* __restrict__ Wxz, const float* __restrict__ Whz, const float* __restrict__ Wmz,
    const float* __restrict__ Wxr, const float* __restrict__ Whr, const float* __restrict__ Wmr,
    const float* __restrict__ Wxh, const float* __restrict__ Whh, const float* __restrict__ Wmh,
    const float* __restrict__ Wgh,
    u16* __restrict__ WZR, u16* __restrict__ WH, u16* __restrict__ WGH)
{
  int t = blockIdx.x * 256 + threadIdx.x;
  const float* src;
  u16* dst;
  if (t < 589824) {
    int row = t / 192;
    int col = (t % 192) * 8;
    int rr = row & 1023;
    const float *wx, *wh, *wm;
    if (row < 1024)      { wx = Wxz; wh = Whz; wm = Wmz; }
    else if (row < 2048) { wx = Wxr; wh = Whr; wm = Wmr; }
    else                 { wx = Wxh; wh = Whh; wm = Wmh; }
    if (col < 256)       src = wx + rr * 256 + col;
    else if (col < 1280) src = wh + (size_t)rr * 1024 + (col - 256);
    else                 src = wm + rr * 256 + (col - 1280);
    dst = (row < 2048) ? (WZR + (size_t)row * 1536 + col)
                       : (WH + (size_t)(row - 2048) * 1536 + col);
  } else {
    int t2 = t - 589824;
    src = Wgh + t2 * 8;
    dst = WGH + t2 * 8;
  }
  f32x4 a = *(const f32x4*)src;
  f32x4 b = *(const f32x4*)(src + 4);
  u16x8 v;
#pragma unroll
  for (int j = 0; j < 4; ++j) { v[j] = f2b(a[j]); v[j + 4] = f2b(b[j]); }
  *(u16x8*)dst = v;
}

// ---------------------------------------------------------------------------
// Elementwise over [B,D]: gamma_x, imputation, x_hat -> X1/X2 cols 0..255 and
// 1280..1535 (m), bf16 delta copy, f32 x_last_obs_new.
// ---------------------------------------------------------------------------
__global__ __launch_bounds__(256) void elem_k(
    const float* __restrict__ x, const float* __restrict__ m, const float* __restrict__ delta,
    const float* __restrict__ xlo, const float* __restrict__ x_mean,
    const float* __restrict__ Wgx, const float* __restrict__ bgx,
    u16* __restrict__ X1, u16* __restrict__ X2, u16* __restrict__ Dbf,
    float* __restrict__ out_xlo)
{
  int t = blockIdx.x * 256 + threadIdx.x;
  int row = t >> 5;
  int col = (t & 31) * 8;
  size_t base = (size_t)row * 256 + col;
  u16x8 vxhat, vm16, vd16;
  f32x4 vlnew[2];
#pragma unroll
  for (int half = 0; half < 2; ++half) {
    f32x4 vx = *(const f32x4*)(x + base + half * 4);
    f32x4 vm = *(const f32x4*)(m + base + half * 4);
    f32x4 vd = *(const f32x4*)(delta + base + half * 4);
    f32x4 vl = *(const f32x4*)(xlo + base + half * 4);
    f32x4 vmean = *(const f32x4*)(x_mean + col + half * 4);
    f32x4 vwg = *(const f32x4*)(Wgx + col + half * 4);
    f32x4 vbg = *(const f32x4*)(bgx + col + half * 4);
#pragma unroll
    for (int j = 0; j < 4; ++j) {
      float mf = vm[j];
      float lnew = (mf > 0.5f) ? vx[j] : vl[j];
      vlnew[half][j] = lnew;
      float gx = __expf(-fmaxf(vd[j] * vwg[j] + vbg[j], 0.0f));
      float ximp = gx * lnew + (1.0f - gx) * vmean[j];
      float xhat = mf * vx[j] + (1.0f - mf) * ximp;
      vxhat[half * 4 + j] = f2b(xhat);
      vm16[half * 4 + j] = f2b(mf);
      vd16[half * 4 + j] = f2b(vd[j]);
    }
  }
  size_t r1536 = (size_t)row * 1536;
  *(u16x8*)(X1 + r1536 + col) = vxhat;
  *(u16x8*)(X2 + r1536 + col) = vxhat;
  *(u16x8*)(X1 + r1536 + 1280 + col) = vm16;
  *(u16x8*)(X2 + r1536 + 1280 + col) = vm16;
  *(u16x8*)(Dbf + base) = vd16;
  *(f32x4*)(out_xlo + base) = vlnew[0];
  *(f32x4*)(out_xlo + base + 4) = vlnew[1];
}

// ---------------------------------------------------------------------------
// Unified 256x128-tile GEMM: C[M,N] = A[M,K] @ W[N,K]^T.
// 8 waves (4Mx2N), per-wave 64x64 (acc 4x4, 16 MFMA/phase), ring-3 of BK=32
// slots (72KB LDS -> 2 blocks/CU = 4 waves/SIMD for nwg>=512).
// Phase u (r9 change: NO wait/barrier between reads and MFMAs):
//   { STAGE unit u+2 -> slot (u+2)%3 ; 8 plain-C++ ds_read_b128 (slot u%3) ;
//     16 MFMA (compiler inserts COUNTED lgkmcnt -> read service overlaps
//     MFMA issue, per-wave and cross-wave) ; vmcnt(3)+lgkmcnt(0) ; BAR }.
// Ledger (identical to r8, which passed): unit u+1 (staged u-1) drained by
//   every wave's vmcnt(3) pre-BAR(u) -> published for reads at u+1. Reads of
//   slot s (phase u) retired by u's trailing lgkm0 pre-BAR(u); restage of s
//   issued at u+1 post-BAR(u) -> ordered. Tail: clamped dummy stages into
//   dead slots keep vmcnt exact; final vmcnt(0) before epilogue.
// Swizzle (0-conflict r2-r8): 16B chunk ^= (row>>1)&3; linear LDS dest +
//   inverse-swizzled global src + swizzled ds_read. XCD-bijective map.
// EPI 0: h_decayed = exp(-relu(.+bgh)) * h      -> X1 cols 256..1279 (bf16)
// EPI 1: cols<1024: z=sigmoid -> Z ; cols>=1024: r*hdec -> X2 cols 256..1279
// EPI 2: h_new = (1-z)*hdec + z*tanh(.+bmh)     -> d_out (f32); A = X2
// ---------------------------------------------------------------------------
template<int EPI, int KK, int GXL>
__global__ __launch_bounds__(512, 4) void gemm256(
    const u16* __restrict__ A, const u16* __restrict__ W,
    const float* __restrict__ bias0, const float* __restrict__ bias1,
    const float* __restrict__ auxf,  // EPI0: h (f32)
    const u16* __restrict__ auxb,    // EPI1/2: X1 (hdec source, bf16)
    const u16* __restrict__ aux2b,   // EPI2: Z (bf16)
    u16* __restrict__ out0b,         // EPI0: X1 ; EPI1: Z
    u16* __restrict__ out1b,         // EPI1: X2
    float* __restrict__ outf)        // EPI2: d_out h_new
{
  constexpr int P = KK / 32;               // phases (one BK=32 unit each)
  constexpr int GX = 1 << GXL;
  __shared__ alignas(16) u16 As[3][8192];  // 256 rows x 32 k (16KB/slot)
  __shared__ alignas(16) u16 Bs[3][4096];  // 128 rows x 32 k ( 8KB/slot)

  const int tid = threadIdx.x, lane = tid & 63, wave = tid >> 6;
  const int wr = wave >> 1, wc = wave & 1;        // 4M x 2N
  const int d = blockIdx.x;
  const int q = (int)gridDim.x >> 3;
  const int L = (d & 7) * q + (d >> 3);           // bijective XCD map
  const int brow = (L >> GXL) * 256, bcol = (L & (GX - 1)) * 128;
  const int lr = lane & 15, g4 = lane >> 4;
  const int rc = (g4 ^ ((lr >> 1) & 3)) * 8;      // swizzled read chunk
  const int srow = tid >> 2;                      // staging row 0..127
  const int scs = ((tid & 3) ^ ((srow >> 1) & 3)) * 8;

  f32x4 acc[4][4];
#pragma unroll
  for (int i = 0; i < 4; ++i)
#pragma unroll
    for (int j = 0; j < 4; ++j) { f32x4 z0 = {0.f, 0.f, 0.f, 0.f}; acc[i][j] = z0; }

  const u16* aP = A + (size_t)(brow + srow) * KK + scs;
  const u16* aQ = aP + (size_t)128 * KK;          // rows 128..255
  const u16* bP = W + (size_t)(bcol + srow) * KK + scs;
  u16* dA = &As[0][0] + tid * 8;                  // lane-linear glds dest
  u16* dB = &Bs[0][0] + tid * 8;
  const u16* rA = &As[0][0] + (wr * 64 + lr) * 32 + rc;
  const u16* rB = &Bs[0][0] + (wc * 64 + lr) * 32 + rc;

  auto STAGE = [&](int slot, int ko) {
    __builtin_amdgcn_global_load_lds(GPTR(aP + ko), LPTR(dA + slot * 8192), 16, 0, 0);
    __builtin_amdgcn_global_load_lds(GPTR(aQ + ko), LPTR(dA + slot * 8192 + 4096), 16, 0, 0);
    __builtin_amdgcn_global_load_lds(GPTR(bP + ko), LPTR(dB + slot * 4096), 16, 0, 0);
  };

  // prologue: units 0,1 -> slots 0,1; drain unit 0; publish
  STAGE(0, 0);
  STAGE(1, 32);
  asm volatile("s_waitcnt vmcnt(3)" ::: "memory");
  BAR;
  asm volatile("" ::: "memory");

#pragma unroll
  for (int u = 0; u < P; ++u) {
    const int sR = u % 3;
    const int sS = (u + 2) % 3;
    const int ko = ((u + 2 < P) ? (u + 2) : (P - 1)) * 32;  // tail: dummy
    STAGE(sS, ko);
    s16x8 af[4], bf[4];
#pragma unroll
    for (int i = 0; i < 4; ++i) af[i] = *(const s16x8*)(rA + sR * 8192 + i * 512);
#pragma unroll
    for (int j = 0; j < 4; ++j) bf[j] = *(const s16x8*)(rB + sR * 4096 + j * 512);
    SETP1;
#pragma unroll
    for (int i = 0; i < 4; ++i)
#pragma unroll
      for (int j = 0; j < 4; ++j)
        acc[i][j] = __builtin_amdgcn_mfma_f32_16x16x32_bf16(af[i], bf[j], acc[i][j], 0, 0, 0);
    SETP0;
    // trailing waits: reads already drained by last MFMA's dependency;
    // this only certifies the slot/ring invariants before the barrier.
    asm volatile("s_waitcnt vmcnt(3) lgkmcnt(0)" ::: "memory");
    BAR;
    asm volatile("" ::: "memory");
  }
  asm volatile("s_waitcnt vmcnt(0)" ::: "memory");  // drain dummy stages

  // epilogue: C/D layout col=lane&15, row=(lane>>4)*4+q  [verified m89/m91]
  const int row0 = brow + wr * 64 + g4 * 4;
  const int col0 = bcol + wc * 64 + lr;
#pragma unroll
  for (int i = 0; i < 4; ++i) {
#pragma unroll
    for (int j = 0; j < 4; ++j) {
      int c_ = col0 + j * 16;
#pragma unroll
      for (int qq = 0; qq < 4; ++qq) {
        int r_ = row0 + i * 16 + qq;
        float v = acc[i][j][qq];
        if constexpr (EPI == 0) {
          float p = v + bias0[c_];
          float gh = __expf(-fmaxf(p, 0.0f));
          float hd = gh * auxf[(size_t)r_ * 1024 + c_];
          out0b[(size_t)r_ * 1536 + 256 + c_] = f2b(hd);
        } else if constexpr (EPI == 1) {
          if (c_ < 1024) {
            out0b[(size_t)r_ * 1024 + c_] = f2b(sigm(v + bias0[c_]));
          } else {
            int jc = c_ - 1024;
            float rg = sigm(v + bias1[jc]);
            float hd = b2f(auxb[(size_t)r_ * 1536 + 256 + jc]);
            out1b[(size_t)r_ * 1536 + 256 + jc] = f2b(rg * hd);
          }
        } else {
          float ht = tanhf(v + bias0[c_]);
          float zz = b2f(aux2b[(size_t)r_ * 1024 + c_]);
          float hd = b2f(auxb[(size_t)r_ * 1536 + 256 + c_]);
          outf[(size_t)r_ * 1024 + c_] = (1.0f - zz) * hd + zz * ht;
        }
      }
    }
  }
}

// ---------------------------------------------------------------------------
extern "C" void kernel_launch(void* const* d_in, const int* in_sizes, int n_in,
                              void* d_out, int out_size, void* d_ws, size_t ws_size,
                              hipStream_t stream)
{
  const float* x     = (const float*)d_in[0];
  const float* m     = (const float*)d_in[1];
  const float* delta = (const float*)d_in[2];
  const float* h     = (const float*)d_in[3];
  const float* xlo   = (const float*)d_in[4];
  const float* xmean = (const float*)d_in[5];
  const float* Wgx   = (const float*)d_in[6];
  const float* bgx   = (const float*)d_in[7];
  const float* Wgh   = (const float*)d_in[8];
  const float* bgh   = (const float*)d_in[9];
  const float* Wxz   = (const float*)d_in[10];
  const float* Whz   = (const float*)d_in[11];
  const float* Wmz   = (const float*)d_in[12];
  const float* bmz   = (const float*)d_in[13];
  const float* Wxr   = (const float*)d_in[14];
  const float* Whr   = (const float*)d_in[15];
  const float* Wmr   = (const float*)d_in[16];
  const float* bmr   = (const float*)d_in[17];
  const float* Wxh   = (const float*)d_in[18];
  const float* Whh   = (const float*)d_in[19];
  const float* Wmh   = (const float*)d_in[20];
  const float* bmh   = (const float*)d_in[21];

  // workspace (bf16): X1[8192,1536] X2[8192,1536] Z[8192,1024]
  //   WZR[2048,1536] WH[1024,1536] Dbf[8192,256] WGH[1024,256]  ~81.3MB
  u16* X1  = (u16*)d_ws;
  u16* X2  = X1 + (size_t)8192 * 1536;
  u16* Z   = X2 + (size_t)8192 * 1536;
  u16* WZR = Z  + (size_t)8192 * 1024;
  u16* WH  = WZR + (size_t)2048 * 1536;
  u16* Dbf = WH + (size_t)1024 * 1536;
  u16* WGH = Dbf + (size_t)8192 * 256;

  float* out_h   = (float*)d_out;
  float* out_xlo = out_h + (size_t)8192 * 1024;

  pack_w<<<2432, 256, 0, stream>>>(Wxz, Whz, Wmz, Wxr, Whr, Wmr, Wxh, Whh, Wmh, Wgh, WZR, WH, WGH);
  elem_k<<<1024, 256, 0, stream>>>(x, m, delta, xlo, xmean, Wgx, bgx, X1, X2, Dbf, out_xlo);
  // GEMM A: gamma_h -> h_decayed into X1[:,256:1280]   (M=8192,N=1024,K=256)
  gemm256<0, 256, 3><<<256, 512, 0, stream>>>(
      Dbf, WGH, bgh, nullptr, h, nullptr, nullptr, X1, nullptr, nullptr);
  // GEMM B: z -> Z ; r*h_decayed -> X2[:,256:1280]     (M=8192,N=2048,K=1536)
  gemm256<1, 1536, 4><<<512, 512, 0, stream>>>(
      X1, WZR, bmz, bmr, nullptr, X1, nullptr, Z, X2, nullptr);
  // GEMM C: h_tilde + final blend -> h_new (f32)       (M=8192,N=1024,K=1536)
  gemm256<2, 1536, 3><<<256, 512, 0, stream>>>(
      X2, WH, bmh, nullptr, nullptr, X1, Z, nullptr, nullptr, out_h);
}